// Round 9
// baseline (202.375 us; speedup 1.0000x reference)
//
#include <hip/hip_runtime.h>
#include <stdint.h>

typedef __bf16 bf16_t;
typedef __bf16 bf16x8 __attribute__((ext_vector_type(8)));
typedef float f32x4 __attribute__((ext_vector_type(4)));

// async global->LDS, 16B per lane; HW dest = wave-uniform base + lane*16
__device__ __forceinline__ void gload_lds16(const void* g, void* l) {
  __builtin_amdgcn_global_load_lds(
      (const __attribute__((address_space(1))) uint32_t*)g,
      (__attribute__((address_space(3))) uint32_t*)l, 16, 0, 0);
}

// ---------------- fused cast f32 -> bf16 for 3 buffers ----------------
__global__ void cast3_f32_bf16(const float* __restrict__ a, bf16_t* __restrict__ ao, int n4a,
                               const float* __restrict__ b, bf16_t* __restrict__ bo, int n4b,
                               const float* __restrict__ c, bf16_t* __restrict__ co, int n4c) {
  int i = blockIdx.x * blockDim.x + threadIdx.x;
  int stride = gridDim.x * blockDim.x;
  int total = n4a + n4b + n4c;
  for (int idx = i; idx < total; idx += stride) {
    const float* src; bf16_t* dst; int j = idx;
    if (j < n4a) { src = a; dst = ao; }
    else if ((j -= n4a) < n4b) { src = b; dst = bo; }
    else { j -= n4b; src = c; dst = co; }
    float4 v = reinterpret_cast<const float4*>(src)[j];
    union { bf16_t b[4]; uint2 u; } pk;
    pk.b[0] = (bf16_t)v.x; pk.b[1] = (bf16_t)v.y;
    pk.b[2] = (bf16_t)v.z; pk.b[3] = (bf16_t)v.w;
    reinterpret_cast<uint2*>(dst)[j] = pk.u;
  }
}

// ---------- 8-phase GEMM: C[M][N] = A[M][K]*B[N][K]^T (+bias) ----------
// BM=BN=256, BK=64, K=1024 (NT=16 tiles, NI=8 iters of 2 tiles).
// 512 thr = 8 waves (2M x 4N), wave tile 128x64; 16 MFMA quadrant per phase.
// LDS: [2 dbuf][2 half(128 rows)] x (A,B) x 16KB = 128KB.
// Phase: {ds_read quadrant | stage 1 half-tile} BAR  setprio(1) 16 MFMA
//        setprio(0) [vmcnt gate @P4/P8] BAR
// NO manual lgkm drain / sched_barrier: ds_reads are compiler-visible, so
// the compiler inserts precise per-operand lgkmcnt(N) waits -> MFMA issue
// overlaps the remaining read drain (the r8 full-drain+pin serialized them).
// Compiler fences (asm ""::memory) flank each raw s_barrier so reads cannot
// move across phases. Safety: each read is consumed by its phase's MFMA =>
// complete before the closing barrier; slot overwrites are >=2 barriers later.
// vmcnt gates (queue: 12 outstanding, oldest 8 = tile needed next): vmcnt(4)
// at P4/P8 steady; vmcnt(0) only last-iter P4. Swizzle: chunk ^= (row&7),
// both sides (pre-swizzled global src + swizzled ds_read) -> 2 lanes/bank.
// Grid: XCD x owns bx slab [x*8,x*8+8) (A-slab 4MB = its L2), bx-fast.
template <bool BF16_OUT>
__global__ __launch_bounds__(512, 2)
void gemm_8ph(const bf16_t* __restrict__ A, const bf16_t* __restrict__ B,
              void* __restrict__ Cout, const float* __restrict__ bias, int N) {
  constexpr int K = 1024, NI = 8;
  __shared__ bf16_t Al[2][2][128 * 64];
  __shared__ bf16_t Bl[2][2][128 * 64];

  const int tid = threadIdx.x;
  const int l = tid & 63, w = tid >> 6;
  const int wm = w >> 2, wn = w & 3;

  const int bid = blockIdx.x;
  const int xcd = bid & 7, idx = bid >> 3;
  const int bx = xcd * 8 + (idx & 7);  // nbx = 64 (M = 16384)
  const int by = idx >> 3;
  const int m0 = bx * 256, n0 = by * 256;

  // staging: thread t covers row (t>>3) of a 64-row issue, lds chunk t&7;
  // global chunk = (t&7) ^ (row&7)  (inverse swizzle)
  const int srow = tid >> 3;
  const int sca = ((tid & 7) ^ (srow & 7)) * 8;
  const bf16_t* pA = A + (size_t)(m0 + srow) * K + sca;
  const bf16_t* pB = B + (size_t)(n0 + srow) * K + sca;

#define ST_A(t_, d_, h_) do {                                                         \
    gload_lds16(pA + (size_t)((h_) * 128) * K + (t_) * 64, &Al[d_][h_][tid * 8]);     \
    gload_lds16(pA + (size_t)((h_) * 128 + 64) * K + (t_) * 64,                       \
                &Al[d_][h_][4096 + tid * 8]); } while (0)
#define ST_B(t_, d_, h_) do {                                                         \
    gload_lds16(pB + (size_t)((h_) * 128) * K + (t_) * 64, &Bl[d_][h_][tid * 8]);     \
    gload_lds16(pB + (size_t)((h_) * 128 + 64) * K + (t_) * 64,                       \
                &Bl[d_][h_][4096 + tid * 8]); } while (0)

  // fragment reads: row = (l&15) + i*16 -> row&7 = l&7
  const int arow = l & 15;
  const int brow = (wn & 1) * 64 + (l & 15);
  const int cks0 = (((l >> 4) + 0) ^ (l & 7)) * 8;
  const int cks1 = (((l >> 4) + 4) ^ (l & 7)) * 8;

#define LDA4(dst, base, i0) do {                                                      \
    _Pragma("unroll") for (int i = 0; i < 4; ++i) {                                   \
      dst[i][0] = *reinterpret_cast<const bf16x8*>(&base[(arow + (i0 + i) * 16) * 64 + cks0]); \
      dst[i][1] = *reinterpret_cast<const bf16x8*>(&base[(arow + (i0 + i) * 16) * 64 + cks1]); \
    } } while (0)
#define LDB2(dst, base, j0) do {                                                      \
    _Pragma("unroll") for (int j = 0; j < 2; ++j) {                                   \
      dst[j][0] = *reinterpret_cast<const bf16x8*>(&base[(brow + (j0 + j) * 16) * 64 + cks0]); \
      dst[j][1] = *reinterpret_cast<const bf16x8*>(&base[(brow + (j0 + j) * 16) * 64 + cks1]); \
    } } while (0)

#define MM16(afr, bfr, I0, J0)                                                        \
    __builtin_amdgcn_s_setprio(1);                                                    \
    _Pragma("unroll") for (int i = 0; i < 4; ++i)                                     \
    _Pragma("unroll") for (int j = 0; j < 2; ++j)                                     \
    _Pragma("unroll") for (int s = 0; s < 2; ++s)                                     \
      acc[I0 + i][J0 + j] = __builtin_amdgcn_mfma_f32_16x16x32_bf16(                  \
          afr[i][s], bfr[j][s], acc[I0 + i][J0 + j], 0, 0, 0);                        \
    __builtin_amdgcn_s_setprio(0);

#define BARF() do { asm volatile("" ::: "memory");                                    \
                    __builtin_amdgcn_s_barrier();                                     \
                    asm volatile("" ::: "memory"); } while (0)

  f32x4 acc[8][4] = {};

  // prologue: tile0 full + tile1 B-halves (12 loads); drain tile0's oldest 8
  ST_A(0, 0, 0); ST_A(0, 0, 1); ST_B(0, 0, 0); ST_B(0, 0, 1);
  ST_B(1, 1, 0); ST_B(1, 1, 1);
  asm volatile("s_waitcnt vmcnt(4)" ::: "memory");
  BARF();

  for (int it = 0; it < NI; ++it) {
    const bool last = (it == NI - 1);
    const int ta = 2 * it, tb = ta + 1;
    const bf16_t* As0 = &Al[0][wm][0];
    const bf16_t* Bs0 = &Bl[0][wn >> 1][0];
    const bf16_t* As1 = &Al[1][wm][0];
    const bf16_t* Bs1 = &Bl[1][wn >> 1][0];
    bf16x8 af0[4][2], af1[4][2], bf0[2][2], bf1[2][2];

    // ---- P1: read bf0-1 + af0-3 (dbuf0) | stage A0(tb)->d1 ----
    LDB2(bf0, Bs0, 0); LDA4(af0, As0, 0);
    ST_A(tb, 1, 0);
    BARF();
    MM16(af0, bf0, 0, 0);
    BARF();
    // ---- P2: read bf2-3 | stage A1(tb)->d1 ----
    LDB2(bf1, Bs0, 2);
    ST_A(tb, 1, 1);
    BARF();
    MM16(af0, bf1, 0, 2);
    BARF();
    // ---- P3: read af4-7 | stage B0(ta+2)->d0 ----
    LDA4(af1, As0, 4);
    if (!last) ST_B(ta + 2, 0, 0);
    BARF();
    MM16(af1, bf0, 4, 0);
    BARF();
    // ---- P4: no reads | stage B1(ta+2)->d0 | vmcnt gate for tile tb ----
    if (!last) ST_B(ta + 2, 0, 1);
    BARF();
    MM16(af1, bf1, 4, 2);
    if (last) asm volatile("s_waitcnt vmcnt(0)" ::: "memory");
    else      asm volatile("s_waitcnt vmcnt(4)" ::: "memory");
    BARF();

    // ---- P5: read bf0-1 + af0-3 (dbuf1) | stage A0(ta+2)->d0 ----
    LDB2(bf0, Bs1, 0); LDA4(af0, As1, 0);
    if (!last) ST_A(ta + 2, 0, 0);
    BARF();
    MM16(af0, bf0, 0, 0);
    BARF();
    // ---- P6: read bf2-3 | stage A1(ta+2)->d0 ----
    LDB2(bf1, Bs1, 2);
    if (!last) ST_A(ta + 2, 0, 1);
    BARF();
    MM16(af0, bf1, 0, 2);
    BARF();
    // ---- P7: read af4-7 | stage B0(tb+2)->d1 ----
    LDA4(af1, As1, 4);
    if (!last) ST_B(tb + 2, 1, 0);
    BARF();
    MM16(af1, bf0, 4, 0);
    BARF();
    // ---- P8: no reads | stage B1(tb+2)->d1 | vmcnt gate for tile ta+2 ----
    if (!last) ST_B(tb + 2, 1, 1);
    BARF();
    MM16(af1, bf1, 4, 2);
    if (!last) asm volatile("s_waitcnt vmcnt(4)" ::: "memory");
    BARF();
  }
#undef ST_A
#undef ST_B
#undef LDA4
#undef LDB2
#undef MM16
#undef BARF

  // ---- epilogue: C/D layout col = lane&15, row = (lane>>4)*4 + reg ----
  const int r0 = m0 + wm * 128 + (l >> 4) * 4;
  const int c0 = n0 + wn * 64 + (l & 15);
  if (BF16_OUT) {
    bf16_t* C = (bf16_t*)Cout;
#pragma unroll
    for (int i = 0; i < 8; ++i)
#pragma unroll
      for (int j = 0; j < 4; ++j)
#pragma unroll
        for (int r = 0; r < 4; ++r)
          C[(size_t)(r0 + i * 16 + r) * N + (c0 + j * 16)] = (bf16_t)acc[i][j][r];
  } else {
    float* C = (float*)Cout;
#pragma unroll
    for (int i = 0; i < 8; ++i)
#pragma unroll
      for (int j = 0; j < 4; ++j)
#pragma unroll
        for (int r = 0; r < 4; ++r)
          C[(size_t)(r0 + i * 16 + r) * N + (c0 + j * 16)] =
              acc[i][j][r] + bias[c0 + j * 16];
  }
}

// ---------------- per-token head-attention ----------------
__global__ __launch_bounds__(256)
void attn_heads(const bf16_t* __restrict__ qkv, bf16_t* __restrict__ out) {
  __shared__ float s[4][3072];
  const int w = threadIdx.x >> 6, l = threadIdx.x & 63;
  const size_t t = (size_t)blockIdx.x * 4 + w;
  const bf16_t* src = qkv + t * 3072;
#pragma unroll
  for (int i = 0; i < 6; ++i) {
    int f = (i * 64 + l) * 8;
    bf16x8 v = *reinterpret_cast<const bf16x8*>(&src[f]);
#pragma unroll
    for (int jj = 0; jj < 8; ++jj) s[w][f + jj] = (float)v[jj];
  }
  __syncthreads();

  const int h = l >> 2, ss = l & 3;
  float qr[16];
  const float* qb = &s[w][h * 192 + ss * 16];
#pragma unroll
  for (int d = 0; d < 16; ++d) qr[d] = qb[d];

  float sc[16];
#pragma unroll
  for (int g = 0; g < 16; ++g) {
    const float* kk = &s[w][g * 192 + 64 + ss * 16];
    float p = 0.f;
#pragma unroll
    for (int d = 0; d < 16; ++d) p += qr[d] * kk[d];
    p += __shfl_xor(p, 1);
    p += __shfl_xor(p, 2);
    sc[g] = p * 0.125f;
  }
  float m = sc[0];
#pragma unroll
  for (int g = 1; g < 16; ++g) m = fmaxf(m, sc[g]);
  float sum = 0.f;
#pragma unroll
  for (int g = 0; g < 16; ++g) { sc[g] = __expf(sc[g] - m); sum += sc[g]; }
  float inv = 1.f / sum;

  float o[16] = {};
#pragma unroll
  for (int g = 0; g < 16; ++g) {
    float a = sc[g] * inv;
    const float* vv = &s[w][g * 192 + 128 + ss * 16];
#pragma unroll
    for (int d = 0; d < 16; ++d) o[d] += a * vv[d];
  }
  union { bf16_t b[16]; uint4 u[2]; } pk;
#pragma unroll
  for (int d = 0; d < 16; ++d) pk.b[d] = (bf16_t)o[d];
  uint4* dst = reinterpret_cast<uint4*>(out + t * 1024 + h * 64 + ss * 16);
  dst[0] = pk.u[0];
  dst[1] = pk.u[1];
}

// ---------------- launch ----------------
extern "C" void kernel_launch(void* const* d_in, const int* in_sizes, int n_in,
                              void* d_out, int out_size, void* d_ws, size_t ws_size,
                              hipStream_t stream) {
  const float* x     = (const float*)d_in[0];  // [8,2048,1024]
  const float* Wqkv  = (const float*)d_in[1];  // [3072,1024]
  const float* Wproj = (const float*)d_in[2];  // [1024,1024]
  const float* bproj = (const float*)d_in[3];  // [1024]
  float* out = (float*)d_out;

  const int M = 8 * 2048;   // 16384 tokens -> 64 bx blocks of 256
  const int DM = 1024;
  const int F = 3072;

  char* ws = (char*)d_ws;
  bf16_t* xb     = (bf16_t*)ws;  ws += (size_t)M * DM * 2;
  bf16_t* wqkvb  = (bf16_t*)ws;  ws += (size_t)F * DM * 2;
  bf16_t* wprojb = (bf16_t*)ws;  ws += (size_t)DM * DM * 2;
  bf16_t* qkvb   = (bf16_t*)ws;  ws += (size_t)M * F * 2;
  bf16_t* attnb  = (bf16_t*)ws;

  cast3_f32_bf16<<<2048, 256, 0, stream>>>(x, xb, M * DM / 4,
                                           Wqkv, wqkvb, F * DM / 4,
                                           Wproj, wprojb, DM * DM / 4);

  // GEMM1: [16384,1024] x [3072,1024]^T -> bf16 [16384,3072]
  gemm_8ph<true><<<(M / 256) * (F / 256), 512, 0, stream>>>(
      xb, wqkvb, (void*)qkvb, nullptr, F);

  attn_heads<<<M / 4, 256, 0, stream>>>(qkvb, attnb);

  // GEMM2: [16384,1024] x [1024,1024]^T -> f32 [16384,1024] + bias
  gemm_8ph<false><<<(M / 256) * (DM / 256), 512, 0, stream>>>(
      attnb, wprojb, (void*)out, bproj, DM);
}